// Round 5
// baseline (397.203 us; speedup 1.0000x reference)
//
#include <hip/hip_runtime.h>
#include <stdint.h>

typedef unsigned short u16;
typedef unsigned int   u32;
using short8 = __attribute__((ext_vector_type(8))) short;   // 8 bf16
using f32x4  = __attribute__((ext_vector_type(4))) float;

__device__ __forceinline__ u16 f2bf(float f){
  u32 u = __builtin_bit_cast(u32, f);
  u = u + 0x7fffu + ((u >> 16) & 1u);     // RNE
  return (u16)(u >> 16);
}
__device__ __forceinline__ u32 packbf2(float a, float b){
  u32 ua = __builtin_bit_cast(u32, a) + 0x8000u;
  u32 ub = __builtin_bit_cast(u32, b) + 0x8000u;
  return (ua >> 16) | (ub & 0xffff0000u);
}

// ---------------------------------------------------------------------------
// K0: folded conv3 A-fragments (identical to R3, correctness-proven).
// Rows pre-scaled by BN scale. K-cols: 0-24 y, 25 bias(x valid), 26-27 lf.
// ---------------------------------------------------------------------------
__global__ void prep_kernel(const float* __restrict__ w3,
                            const float* __restrict__ w1,
                            const float* __restrict__ b1,
                            const float* __restrict__ bng,
                            const float* __restrict__ bnv,
                            u16* __restrict__ convA)
{
  int idx = blockIdx.x*256 + threadIdx.x;
  if (idx >= 4*2*3*64*8) return;
  int j = idx & 7, l = (idx>>3) & 63, frag = idx >> 9;
  int tap = frag % 3, mt = (frag/3) & 1, lay = frag/6;
  int m = mt*16 + (l & 15);
  int k = (l>>4)*8 + j;
  float v = 0.f;
  if (m < 25){
    float a = bng[lay*25+m] * rsqrtf(bnv[lay*25+m] + 1e-5f);
    if (k < 25){
      v = a * w3[((lay*25+m)*25 + k)*3 + tap];
    } else if (k == 25){
      float s = 0.f;
      for (int c = 0; c < 25; ++c) s += w3[((lay*25+m)*25+c)*3+tap] * b1[lay*25+c];
      v = a * s;
    } else if (k <= 27){
      int e = k - 26;
      float s = 0.f;
      for (int c = 0; c < 25; ++c) s += w3[((lay*25+m)*25+c)*3+tap] * w1[(lay*25+c)*2+e];
      v = a * s;
    }
  }
  convA[idx] = f2bf(v);
}

// ---------------------------------------------------------------------------
// pass_kernel<PASS>: per-wave 64-col window (4 MFMA tiles), interior 32 cols
// (16..47), margin 16 each side (= R3's proven margin). Ping-pong z buffers.
// PASS1: conv chain -> per-channel sums (gate numerator).
// PASS2: conv chain + fused gated proj GEMM (B straight from z) + pooled.
// ---------------------------------------------------------------------------
template<int PASS>
__global__ __launch_bounds__(256, (PASS==1) ? 3 : 2)
void pass_kernel(const float* __restrict__ lfg,
                 const float* __restrict__ w1g, const float* __restrict__ b1g,
                 const float* __restrict__ b3g,
                 const float* __restrict__ bng, const float* __restrict__ bnb,
                 const float* __restrict__ bnm, const float* __restrict__ bnv,
                 const u16* __restrict__ convA, const u16* __restrict__ Ab,
                 const float* __restrict__ pfb, const float* __restrict__ idb,
                 const float* __restrict__ fbg, const float* __restrict__ fbb,
                 const float* __restrict__ fbm, const float* __restrict__ fbv,
                 float* __restrict__ outpart)
{
  constexpr int CZ = 66;               // 64 cols + 2 guards
  __shared__ __align__(16) u16 zws[4][2][CZ*40];     // 42.2 KB
  __shared__ __align__(16) float cAs[4][32];
  __shared__ __align__(16) float w4as[32], w4bs[32], c4s[32];
  __shared__ float accC[(PASS==1)?160:4];
  __shared__ __align__(16) float AfS[(PASS==2)?128:4], BfS[(PASS==2)?128:4];

  const int tid  = threadIdx.x;
  const int lane = tid & 63, wv = tid >> 6;
  const int q = lane >> 4, c16 = lane & 15;
  const int b = blockIdx.y, blk = blockIdx.x;
  const int s = blk*4 + wv;
  const int tbase = s*32 - 16;         // t of window col 0; interior cols 16..47

  for (int x = tid; x < 4*2*CZ*20; x += 256) ((u32*)zws)[x] = 0u;
  __syncthreads();
  for (int x = tid; x < 4*2*CZ; x += 256){           // valid-indicator rows
    int w = x/(2*CZ), rb = (x/CZ)&1, cz = x%CZ;
    int t = (blk*4+w)*32 - 16 + cz - 1;
    zws[w][rb][cz*40 + 25] = ((unsigned)t < 4096u) ? (u16)0x3F80 : (u16)0;
  }
  if (tid < 128){
    int i = tid >> 5, ch = tid & 31;
    float cc = 0.f;
    if (ch < 25){
      float a = bng[i*25+ch]*rsqrtf(bnv[i*25+ch]+1e-5f);
      cc = (b3g[i*25+ch] - bnm[i*25+ch])*a + bnb[i*25+ch];
    }
    cAs[i][ch] = cc;
  } else if (tid < 160){
    int ch = tid - 128;
    float wa=0.f, wb=0.f, cf=0.f;
    if (ch < 25){
      float a = bng[100+ch]*rsqrtf(bnv[100+ch]+1e-5f);
      wa = a*w1g[(100+ch)*2+0]; wb = a*w1g[(100+ch)*2+1];
      cf = a*b1g[100+ch] + (bnb[100+ch] - bnm[100+ch]*a);
    }
    w4as[ch]=wa; w4bs[ch]=wb; c4s[ch]=cf;
  }
  if constexpr (PASS==1){ if (tid < 160) accC[tid] = 0.f; }
  if constexpr (PASS==2){
    if (tid < 128){
      float fs=0.f, fsh=0.f;
      if (tid < 125){
        fs  = fbg[tid]*rsqrtf(fbv[tid]+1e-5f);
        fsh = (pfb[tid]+idb[tid]-fbm[tid])*fs + fbb[tid];
      }
      AfS[tid]=fs; BfS[tid]=fsh;
    }
  }
  __syncthreads();

  const float* lfb = lfg + b*10*4096;

  // lf pairs: lpair[k] = pack(lf[2k], lf[2k+1]) at window col = lane (0..63)
  u32 lpair[4];
  {
    int t = tbase + lane;
    bool ok = (unsigned)t < 4096u;
    #pragma unroll
    for (int k = 0; k < 4; ++k){
      float a = ok ? lfb[(2*k  )*4096 + t] : 0.f;
      float c = ok ? lfb[(2*k+1)*4096 + t] : 0.f;
      lpair[k] = packbf2(a, c);
    }
  }

  f32x4 pacc[2][8];
  if constexpr (PASS==2){
    #pragma unroll
    for (int n2=0;n2<2;++n2)
      #pragma unroll
      for (int m2=0;m2<8;++m2) pacc[n2][m2] = (f32x4){0.f,0.f,0.f,0.f};
  }

  u16* bufA = zws[wv][0];

  // ---------------- prologue: y4 = relu(folded 1x1) over 64 cols -----------
  {
    const f32x4 wa0 = *(const f32x4*)&w4as[4*q];
    const f32x4 wa1 = *(const f32x4*)&w4as[16+4*q];
    const f32x4 wb0 = *(const f32x4*)&w4bs[4*q];
    const f32x4 wb1 = *(const f32x4*)&w4bs[16+4*q];
    const f32x4 cf0 = *(const f32x4*)&c4s[4*q];
    const f32x4 cf1 = *(const f32x4*)&c4s[16+4*q];
    float s4[8];
    #pragma unroll
    for (int e=0;e<8;++e) s4[e] = 0.f;
    #pragma unroll
    for (int ct=0; ct<4; ++ct){
      const int wc = 16*ct + c16;
      const int t  = tbase + wc;
      const bool tok = (unsigned)t < 4096u;
      const float l8 = tok ? lfb[8*4096 + t] : 0.f;
      const float l9 = tok ? lfb[9*4096 + t] : 0.f;
      float y0[4], y1[4];
      #pragma unroll
      for (int r=0;r<4;++r){
        float a = fmaxf(wa0[r]*l8 + wb0[r]*l9 + cf0[r], 0.f);
        float c = fmaxf(wa1[r]*l8 + wb1[r]*l9 + cf1[r], 0.f);
        y0[r] = tok ? a : 0.f;
        y1[r] = tok ? c : 0.f;
      }
      if (PASS==1 && (ct==1 || ct==2)){
        #pragma unroll
        for (int r=0;r<4;++r){ s4[r] += y0[r]; s4[4+r] += y1[r]; }
      }
      uint2 w0; w0.x = packbf2(y0[0],y0[1]); w0.y = packbf2(y0[2],y0[3]);
      *(uint2*)&bufA[(wc+1)*40 + 4*q] = w0;
      if (q < 2){
        uint2 w1_; w1_.x = packbf2(y1[0],y1[1]); w1_.y = packbf2(y1[2],y1[3]);
        *(uint2*)&bufA[(wc+1)*40 + 16 + 4*q] = w1_;
      } else if (q == 2){
        bufA[(wc+1)*40 + 24] = f2bf(y1[0]);
      }
    }
    *(u32*)&bufA[(lane+1)*40 + 26] = lpair[3];        // lf for layer 3
    if constexpr (PASS==1){
      #pragma unroll
      for (int e=0;e<8;++e){
        float v = s4[e];
        v += __shfl_xor(v,1); v += __shfl_xor(v,2); v += __shfl_xor(v,4); v += __shfl_xor(v,8);
        if (c16 == 0){
          int ch = (e>>2)*16 + 4*q + (e&3);
          if (ch < 25) atomicAdd(&accC[4*32+ch], v);
        }
      }
    }
  }

  if constexpr (PASS==2){
    { // GEMM kt=4 : B = y4 from bufA interior (cols 16..47)
      short8 Am[8];
      #pragma unroll
      for (int m2=0;m2<8;++m2)
        Am[m2] = *(const short8*)(Ab + b*24576 + ((4*8+m2)*64 + lane)*8);
      #pragma unroll
      for (int n2=0;n2<2;++n2){
        const short8 Bm = *(const short8*)&bufA[(17+16*n2+c16)*40 + 8*q];
        #pragma unroll
        for (int m2=0;m2<8;++m2)
          pacc[n2][m2] = __builtin_amdgcn_mfma_f32_16x16x32_bf16(Am[m2], Bm, pacc[n2][m2],0,0,0);
      }
    }
    { // GEMM kt=5 : identity from lf
      short8 Am[8];
      #pragma unroll
      for (int m2=0;m2<8;++m2)
        Am[m2] = *(const short8*)(Ab + b*24576 + ((5*8+m2)*64 + lane)*8);
      #pragma unroll
      for (int n2=0;n2<2;++n2){
        const int t = tbase + 16 + 16*n2 + c16;
        u32 bw[4];
        #pragma unroll
        for (int p=0;p<4;++p){
          int k0 = 8*q + 2*p;
          float v0 = (k0   < 10) ? lfb[k0*4096 + t] : 0.f;
          float v1 = (k0+1 < 10) ? lfb[(k0+1)*4096 + t] : 0.f;
          bw[p] = packbf2(v0, v1);
        }
        const short8 Bm = __builtin_bit_cast(short8, bw);
        #pragma unroll
        for (int m2=0;m2<8;++m2)
          pacc[n2][m2] = __builtin_amdgcn_mfma_f32_16x16x32_bf16(Am[m2], Bm, pacc[n2][m2],0,0,0);
      }
    }
  }

  // ---------------- conv layers i = 3..0, ping-pong z ----------------------
  #pragma unroll
  for (int i = 3; i >= 0; --i){
    u16* src = zws[wv][(3-i)&1];
    u16* dst = zws[wv][(4-i)&1];
    short8 Ac0[3], Ac1[3];
    #pragma unroll
    for (int tp=0;tp<3;++tp){
      Ac0[tp] = *(const short8*)(convA + (((i*2+0)*3+tp)*64 + lane)*8);
      Ac1[tp] = *(const short8*)(convA + (((i*2+1)*3+tp)*64 + lane)*8);
    }
    const f32x4 cc0 = *(const f32x4*)&cAs[i][4*q];
    const f32x4 cc1 = *(const f32x4*)&cAs[i][16+4*q];
    float ysum[8];
    #pragma unroll
    for (int e=0;e<8;++e) ysum[e] = 0.f;

    #pragma unroll
    for (int ct=0; ct<4; ++ct){
      const int wc = 16*ct + c16;
      const u16* p = src + wc*40 + 8*q;       // taps: cols wc-1, wc, wc+1
      short8 t0 = *(const short8*)(p);
      short8 t1 = *(const short8*)(p + 40);
      short8 t2 = *(const short8*)(p + 80);
      f32x4 a0 = {0.f,0.f,0.f,0.f}, a1 = {0.f,0.f,0.f,0.f};
      a0 = __builtin_amdgcn_mfma_f32_16x16x32_bf16(Ac0[0], t0, a0, 0,0,0);
      a1 = __builtin_amdgcn_mfma_f32_16x16x32_bf16(Ac1[0], t0, a1, 0,0,0);
      a0 = __builtin_amdgcn_mfma_f32_16x16x32_bf16(Ac0[1], t1, a0, 0,0,0);
      a1 = __builtin_amdgcn_mfma_f32_16x16x32_bf16(Ac1[1], t1, a1, 0,0,0);
      a0 = __builtin_amdgcn_mfma_f32_16x16x32_bf16(Ac0[2], t2, a0, 0,0,0);
      a1 = __builtin_amdgcn_mfma_f32_16x16x32_bf16(Ac1[2], t2, a1, 0,0,0);
      const int t = tbase + wc;
      const bool tok = (unsigned)t < 4096u;
      float y0[4], y1[4];
      #pragma unroll
      for (int r=0;r<4;++r){
        float u0 = fmaxf(a0[r] + cc0[r], 0.f);
        float u1 = fmaxf(a1[r] + cc1[r], 0.f);
        y0[r] = tok ? u0 : 0.f;
        y1[r] = tok ? u1 : 0.f;
      }
      if (PASS==1 && (ct==1 || ct==2)){
        #pragma unroll
        for (int r=0;r<4;++r){ ysum[r] += y0[r]; ysum[4+r] += y1[r]; }
      }
      uint2 w0; w0.x = packbf2(y0[0],y0[1]); w0.y = packbf2(y0[2],y0[3]);
      *(uint2*)&dst[(wc+1)*40 + 4*q] = w0;
      if (q < 2){
        uint2 w1_; w1_.x = packbf2(y1[0],y1[1]); w1_.y = packbf2(y1[2],y1[3]);
        *(uint2*)&dst[(wc+1)*40 + 16 + 4*q] = w1_;
      } else if (q == 2){
        dst[(wc+1)*40 + 24] = f2bf(y1[0]);
      }
    }
    if (i > 0) *(u32*)&dst[(lane+1)*40 + 26] = lpair[i-1];
    if constexpr (PASS==1){
      #pragma unroll
      for (int e=0;e<8;++e){
        float v = ysum[e];
        v += __shfl_xor(v,1); v += __shfl_xor(v,2); v += __shfl_xor(v,4); v += __shfl_xor(v,8);
        if (c16 == 0){
          int ch = (e>>2)*16 + 4*q + (e&3);
          if (ch < 25) atomicAdd(&accC[i*32+ch], v);
        }
      }
    }
    if constexpr (PASS==2){                 // GEMM kt=i : B = y_i from dst
      short8 Am[8];
      #pragma unroll
      for (int m2=0;m2<8;++m2)
        Am[m2] = *(const short8*)(Ab + b*24576 + ((i*8+m2)*64 + lane)*8);
      #pragma unroll
      for (int n2=0;n2<2;++n2){
        const short8 Bm = *(const short8*)&dst[(17+16*n2+c16)*40 + 8*q];
        #pragma unroll
        for (int m2=0;m2<8;++m2)
          pacc[n2][m2] = __builtin_amdgcn_mfma_f32_16x16x32_bf16(Am[m2], Bm, pacc[n2][m2],0,0,0);
      }
    }
  }

  if constexpr (PASS==1){
    __syncthreads();
    if (tid < 160) outpart[(b*32 + blk)*160 + tid] = accC[tid];
  }
  if constexpr (PASS==2){
    f32x4 ps[8];
    #pragma unroll
    for (int m2=0;m2<8;++m2){
      const f32x4 af = *(const f32x4*)&AfS[m2*16+4*q];
      const f32x4 bf = *(const f32x4*)&BfS[m2*16+4*q];
      #pragma unroll
      for (int r=0;r<4;++r){
        float s2 = fmaxf(pacc[0][m2][r]*af[r] + bf[r], 0.f)
                 + fmaxf(pacc[1][m2][r]*af[r] + bf[r], 0.f);
        s2 += __shfl_xor(s2,1); s2 += __shfl_xor(s2,2); s2 += __shfl_xor(s2,4); s2 += __shfl_xor(s2,8);
        ps[m2][r] = s2;
      }
    }
    if (c16 == 0){
      const int widx = (b*32 + blk)*4 + wv;
      #pragma unroll
      for (int m2=0;m2<8;++m2)
        *(f32x4*)&outpart[widx*128 + m2*16 + 4*q] = ps[m2];
    }
  }
}

// ---------------------------------------------------------------------------
// K2: gating MLP + per-batch gated proj A-fragments (kt 0-4 gated, kt 5 id)
// ---------------------------------------------------------------------------
__global__ void gate_kernel(const float* __restrict__ partialC,
                            const float* __restrict__ gw1, const float* __restrict__ gb1,
                            const float* __restrict__ gw2, const float* __restrict__ gb2,
                            const float* __restrict__ pf_w, const float* __restrict__ id_w,
                            u16* __restrict__ Ab)
{
  int b = blockIdx.x, tid = threadIdx.x;
  __shared__ float avg[125], h1[31], g[6];
  if (tid < 160){
    float s = 0.f;
    for (int k = 0; k < 32; ++k) s += partialC[(b*32+k)*160 + tid];
    int sc = tid >> 5, ch = tid & 31;
    if (ch < 25) avg[sc*25+ch] = s * (1.f/4096.f);
  }
  __syncthreads();
  if (tid < 31){
    float s = gb1[tid];
    for (int c = 0; c < 125; ++c) s += avg[c] * gw1[tid*125 + c];
    h1[tid] = fmaxf(s, 0.f);
  }
  __syncthreads();
  if (tid < 5){
    float s = gb2[tid];
    for (int j = 0; j < 31; ++j) s += h1[j] * gw2[tid*31 + j];
    g[tid] = 1.f / (1.f + expf(-s));
  }
  if (tid == 5) g[5] = 1.f;
  __syncthreads();
  for (int idx = tid; idx < 24576; idx += 256){
    int j = idx & 7, l = (idx>>3) & 63, mt = (idx>>9) & 7, kt = idx >> 12;
    int m = mt*16 + (l & 15), k = (l>>4)*8 + j;
    float v = 0.f;
    if (m < 125){
      if (kt < 5){ if (k < 25) v = pf_w[m*125 + kt*25 + k] * g[kt]; }
      else       { if (k < 10) v = id_w[m*10 + k]; }
    }
    Ab[b*24576 + idx] = f2bf(v);
  }
}

// ---------------------------------------------------------------------------
// K4: pooled mean -> LayerNorm -> fc1 + LeakyReLU(0.2) -> fc2
// ---------------------------------------------------------------------------
__global__ void final_kernel(const float* __restrict__ pooledpart,
                             const float* __restrict__ ln_g, const float* __restrict__ ln_b,
                             const float* __restrict__ fc1_w, const float* __restrict__ fc1_b,
                             const float* __restrict__ fc2_w, const float* __restrict__ fc2_b,
                             float* __restrict__ out)
{
  int b = blockIdx.x, tid = threadIdx.x;
  __shared__ float pl[125], nr[125], hh[64], st[2];
  for (int c = tid; c < 125; c += 64){
    float s = 0.f;
    for (int k = 0; k < 128; ++k) s += pooledpart[(b*128+k)*128 + c];
    pl[c] = s * (1.f/4096.f);
  }
  __syncthreads();
  if (tid == 0){
    float mu = 0.f;
    for (int c = 0; c < 125; ++c) mu += pl[c];
    mu /= 125.f;
    float va = 0.f;
    for (int c = 0; c < 125; ++c){ float d = pl[c] - mu; va += d*d; }
    va /= 125.f;
    st[0] = mu; st[1] = rsqrtf(va + 1e-5f);
  }
  __syncthreads();
  for (int c = tid; c < 125; c += 64)
    nr[c] = (pl[c] - st[0]) * st[1] * ln_g[c] + ln_b[c];
  __syncthreads();
  {
    float s = fc1_b[tid];
    for (int c = 0; c < 125; ++c) s += nr[c] * fc1_w[tid*125 + c];
    hh[tid] = (s > 0.f) ? s : 0.2f * s;
  }
  __syncthreads();
  if (tid < 2){
    float s = fc2_b[tid];
    for (int j = 0; j < 64; ++j) s += hh[j] * fc2_w[tid*64 + j];
    out[b*2 + tid] = s;
  }
}

// ---------------------------------------------------------------------------
extern "C" void kernel_launch(void* const* d_in, const int* in_sizes, int n_in,
                              void* d_out, int out_size, void* d_ws, size_t ws_size,
                              hipStream_t stream)
{
  const float* lf    = (const float*)d_in[0];
  const float* w1    = (const float*)d_in[1];
  const float* b1    = (const float*)d_in[2];
  const float* w3    = (const float*)d_in[3];
  const float* b3    = (const float*)d_in[4];
  const float* bn_g  = (const float*)d_in[5];
  const float* bn_b  = (const float*)d_in[6];
  const float* bn_m  = (const float*)d_in[7];
  const float* bn_v  = (const float*)d_in[8];
  const float* gw1   = (const float*)d_in[9];
  const float* gb1   = (const float*)d_in[10];
  const float* gw2   = (const float*)d_in[11];
  const float* gb2   = (const float*)d_in[12];
  const float* id_w  = (const float*)d_in[13];
  const float* id_b  = (const float*)d_in[14];
  const float* pf_w  = (const float*)d_in[15];
  const float* pf_b  = (const float*)d_in[16];
  const float* fbn_g = (const float*)d_in[17];
  const float* fbn_b = (const float*)d_in[18];
  const float* fbn_m = (const float*)d_in[19];
  const float* fbn_v = (const float*)d_in[20];
  const float* ln_g  = (const float*)d_in[21];
  const float* ln_b  = (const float*)d_in[22];
  const float* fc1_w = (const float*)d_in[23];
  const float* fc1_b = (const float*)d_in[24];
  const float* fc2_w = (const float*)d_in[25];
  const float* fc2_b = (const float*)d_in[26];

  char* ws = (char*)d_ws;
  float* partialC   = (float*)ws;                                   // 2,621,440 B
  float* pooledpart = (float*)(ws + 2621440);                       // 8,388,608 B
  u16*   Ab         = (u16*)(ws + 2621440 + 8388608);               // 6,291,456 B
  u16*   convA      = (u16*)(ws + 2621440 + 8388608 + 6291456);     //    24,576 B

  prep_kernel<<<48, 256, 0, stream>>>(w3, w1, b1, bn_g, bn_v, convA);
  pass_kernel<1><<<dim3(32,128), 256, 0, stream>>>(lf, w1, b1, b3, bn_g, bn_b,
      bn_m, bn_v, convA, Ab, pf_b, id_b, fbn_g, fbn_b, fbn_m, fbn_v, partialC);
  gate_kernel<<<128, 256, 0, stream>>>(partialC, gw1, gb1, gw2, gb2, pf_w, id_w, Ab);
  pass_kernel<2><<<dim3(32,128), 256, 0, stream>>>(lf, w1, b1, b3, bn_g, bn_b,
      bn_m, bn_v, convA, Ab, pf_b, id_b, fbn_g, fbn_b, fbn_m, fbn_v, pooledpart);
  final_kernel<<<128, 64, 0, stream>>>(pooledpart, ln_g, ln_b, fc1_w, fc1_b,
      fc2_w, fc2_b, (float*)d_out);
}

// Round 6
// 377.366 us; speedup vs baseline: 1.0526x; 1.0526x over previous
//
#include <hip/hip_runtime.h>
#include <stdint.h>

typedef unsigned short u16;
typedef unsigned int   u32;
using short8 = __attribute__((ext_vector_type(8))) short;   // 8 bf16
using f32x4  = __attribute__((ext_vector_type(4))) float;

__device__ __forceinline__ u16 f2bf(float f){
  u32 u = __builtin_bit_cast(u32, f);
  u = u + 0x7fffu + ((u >> 16) & 1u);     // RNE
  return (u16)(u >> 16);
}
__device__ __forceinline__ u32 packbf2(float a, float b){
  u32 ua = __builtin_bit_cast(u32, a) + 0x8000u;
  u32 ub = __builtin_bit_cast(u32, b) + 0x8000u;
  return (ua >> 16) | (ub & 0xffff0000u);
}

// ---------------------------------------------------------------------------
// K0: folded conv3 A-fragments (proven R3/R5). Rows pre-scaled by BN scale.
// K-cols: 0-24 y, 25 bias(x valid-row), 26-27 lf rows. 28-31 zero.
// ---------------------------------------------------------------------------
__global__ void prep_kernel(const float* __restrict__ w3,
                            const float* __restrict__ w1,
                            const float* __restrict__ b1,
                            const float* __restrict__ bng,
                            const float* __restrict__ bnv,
                            u16* __restrict__ convA)
{
  int idx = blockIdx.x*256 + threadIdx.x;
  if (idx >= 4*2*3*64*8) return;
  int j = idx & 7, l = (idx>>3) & 63, frag = idx >> 9;
  int tap = frag % 3, mt = (frag/3) & 1, lay = frag/6;
  int m = mt*16 + (l & 15);
  int k = (l>>4)*8 + j;
  float v = 0.f;
  if (m < 25){
    float a = bng[lay*25+m] * rsqrtf(bnv[lay*25+m] + 1e-5f);
    if (k < 25){
      v = a * w3[((lay*25+m)*25 + k)*3 + tap];
    } else if (k == 25){
      float s = 0.f;
      for (int c = 0; c < 25; ++c) s += w3[((lay*25+m)*25+c)*3+tap] * b1[lay*25+c];
      v = a * s;
    } else if (k <= 27){
      int e = k - 26;
      float s = 0.f;
      for (int c = 0; c < 25; ++c) s += w3[((lay*25+m)*25+c)*3+tap] * w1[(lay*25+c)*2+e];
      v = a * s;
    }
  }
  convA[idx] = f2bf(v);
}

// ---------------------------------------------------------------------------
// pass_kernel<PASS>: per-wave 64-col window (4 tiles), interior cols 16..47,
// margin 16 (proven). SINGLE in-place z buffer + 2-ahead tap prefetch ring +
// sched_barrier(0) (R3-proven ordering). BN shift pre-loaded into MFMA acc.
// ---------------------------------------------------------------------------
template<int PASS>
__global__ __launch_bounds__(256, (PASS==1) ? 4 : 2)
void pass_kernel(const float* __restrict__ lfg,
                 const float* __restrict__ w1g, const float* __restrict__ b1g,
                 const float* __restrict__ b3g,
                 const float* __restrict__ bng, const float* __restrict__ bnb,
                 const float* __restrict__ bnm, const float* __restrict__ bnv,
                 const u16* __restrict__ convA, const u16* __restrict__ Ab,
                 const float* __restrict__ pfb, const float* __restrict__ idb,
                 const float* __restrict__ fbg, const float* __restrict__ fbb,
                 const float* __restrict__ fbm, const float* __restrict__ fbv,
                 float* __restrict__ outpart)
{
  constexpr int CZ = 66;               // 64 cols + 2 guards
  __shared__ __align__(16) u16 zws[4][CZ*40];        // 21.1 KB single buffer
  __shared__ __align__(16) float cAs[4][32];
  __shared__ __align__(16) float w4as[32], w4bs[32], c4s[32];
  __shared__ float accC[(PASS==1)?160:4];
  __shared__ float pooled[(PASS==2)?128:4];
  __shared__ __align__(16) float AfS[(PASS==2)?128:4], BfS[(PASS==2)?128:4];

  const int tid  = threadIdx.x;
  const int lane = tid & 63, wv = tid >> 6;
  const int q = lane >> 4, c16 = lane & 15;
  const int b = blockIdx.y, blk = blockIdx.x;
  const int s = blk*4 + wv;
  const int tbase = s*32 - 16;         // t of window col 0; interior cols 16..47

  for (int x = tid; x < 4*CZ*20; x += 256) ((u32*)zws)[x] = 0u;
  __syncthreads();
  for (int x = tid; x < 4*CZ; x += 256){             // valid-indicator rows
    int w = x/CZ, cz = x%CZ;
    int t = (blk*4+w)*32 - 16 + cz - 1;
    zws[w][cz*40 + 25] = ((unsigned)t < 4096u) ? (u16)0x3F80 : (u16)0;
  }
  if (tid < 128){
    int i = tid >> 5, ch = tid & 31;
    float cc = 0.f;
    if (ch < 25){
      float a = bng[i*25+ch]*rsqrtf(bnv[i*25+ch]+1e-5f);
      cc = (b3g[i*25+ch] - bnm[i*25+ch])*a + bnb[i*25+ch];
    }
    cAs[i][ch] = cc;
  } else if (tid < 160){
    int ch = tid - 128;
    float wa=0.f, wb=0.f, cf=0.f;
    if (ch < 25){
      float a = bng[100+ch]*rsqrtf(bnv[100+ch]+1e-5f);
      wa = a*w1g[(100+ch)*2+0]; wb = a*w1g[(100+ch)*2+1];
      cf = a*b1g[100+ch] + (bnb[100+ch] - bnm[100+ch]*a);
    }
    w4as[ch]=wa; w4bs[ch]=wb; c4s[ch]=cf;
  }
  if constexpr (PASS==1){ if (tid < 160) accC[tid] = 0.f; }
  if constexpr (PASS==2){
    if (tid < 128){
      pooled[tid] = 0.f;
      float fs=0.f, fsh=0.f;
      if (tid < 125){
        fs  = fbg[tid]*rsqrtf(fbv[tid]+1e-5f);
        fsh = (pfb[tid]+idb[tid]-fbm[tid])*fs + fbb[tid];
      }
      AfS[tid]=fs; BfS[tid]=fsh;
    }
  }
  __syncthreads();

  const float* lfb = lfg + b*10*4096;

  // lf pairs: lpair[k] = pack(lf[2k], lf[2k+1]) at window col = lane (0..63)
  u32 lpair[4];
  {
    int t = tbase + lane;
    bool ok = (unsigned)t < 4096u;
    #pragma unroll
    for (int k = 0; k < 4; ++k){
      float a = ok ? lfb[(2*k  )*4096 + t] : 0.f;
      float c = ok ? lfb[(2*k+1)*4096 + t] : 0.f;
      lpair[k] = packbf2(a, c);
    }
  }

  f32x4 pacc[2][8];
  if constexpr (PASS==2){
    #pragma unroll
    for (int n2=0;n2<2;++n2)
      #pragma unroll
      for (int m2=0;m2<8;++m2) pacc[n2][m2] = (f32x4){0.f,0.f,0.f,0.f};
  }

  u16* z = zws[wv];

  // ---------------- prologue: y4 = relu(folded 1x1) over 64 cols -----------
  {
    const f32x4 wa0 = *(const f32x4*)&w4as[4*q];
    const f32x4 wa1 = *(const f32x4*)&w4as[16+4*q];
    const f32x4 wb0 = *(const f32x4*)&w4bs[4*q];
    const f32x4 wb1 = *(const f32x4*)&w4bs[16+4*q];
    const f32x4 cf0 = *(const f32x4*)&c4s[4*q];
    const f32x4 cf1 = *(const f32x4*)&c4s[16+4*q];
    float s4[8];
    #pragma unroll
    for (int e=0;e<8;++e) s4[e] = 0.f;
    #pragma unroll
    for (int ct=0; ct<4; ++ct){
      const int wc = 16*ct + c16;
      const int t  = tbase + wc;
      const bool tok = (unsigned)t < 4096u;
      const float l8 = tok ? lfb[8*4096 + t] : 0.f;
      const float l9 = tok ? lfb[9*4096 + t] : 0.f;
      float y0[4], y1[4];
      #pragma unroll
      for (int r=0;r<4;++r){
        float a = fmaxf(wa0[r]*l8 + wb0[r]*l9 + cf0[r], 0.f);
        float c = fmaxf(wa1[r]*l8 + wb1[r]*l9 + cf1[r], 0.f);
        y0[r] = tok ? a : 0.f;
        y1[r] = tok ? c : 0.f;
      }
      if (PASS==1 && (ct==1 || ct==2)){
        #pragma unroll
        for (int r=0;r<4;++r){ s4[r] += y0[r]; s4[4+r] += y1[r]; }
      }
      uint2 w0; w0.x = packbf2(y0[0],y0[1]); w0.y = packbf2(y0[2],y0[3]);
      *(uint2*)&z[(wc+1)*40 + 4*q] = w0;
      if (q < 2){
        uint2 w1_; w1_.x = packbf2(y1[0],y1[1]); w1_.y = packbf2(y1[2],y1[3]);
        *(uint2*)&z[(wc+1)*40 + 16 + 4*q] = w1_;
      } else if (q == 2){
        z[(wc+1)*40 + 24] = f2bf(y1[0]);
      }
    }
    *(u32*)&z[(lane+1)*40 + 26] = lpair[3];           // lf for layer 3
    if constexpr (PASS==1){
      #pragma unroll
      for (int e=0;e<8;++e){
        float v = s4[e];
        v += __shfl_xor(v,1); v += __shfl_xor(v,2); v += __shfl_xor(v,4); v += __shfl_xor(v,8);
        if (c16 == 0){
          int ch = (e>>2)*16 + 4*q + (e&3);
          if (ch < 25) atomicAdd(&accC[4*32+ch], v);
        }
      }
    }
  }

  if constexpr (PASS==2){
    { // GEMM kt=4 : B = y4 from z interior (cols 16..47)
      short8 Am[8];
      #pragma unroll
      for (int m2=0;m2<8;++m2)
        Am[m2] = *(const short8*)(Ab + b*24576 + ((4*8+m2)*64 + lane)*8);
      #pragma unroll
      for (int n2=0;n2<2;++n2){
        const short8 Bm = *(const short8*)&z[(17+16*n2+c16)*40 + 8*q];
        #pragma unroll
        for (int m2=0;m2<8;++m2)
          pacc[n2][m2] = __builtin_amdgcn_mfma_f32_16x16x32_bf16(Am[m2], Bm, pacc[n2][m2],0,0,0);
      }
    }
    { // GEMM kt=5 : identity from lf
      short8 Am[8];
      #pragma unroll
      for (int m2=0;m2<8;++m2)
        Am[m2] = *(const short8*)(Ab + b*24576 + ((5*8+m2)*64 + lane)*8);
      #pragma unroll
      for (int n2=0;n2<2;++n2){
        const int t = tbase + 16 + 16*n2 + c16;
        u32 bw[4];
        #pragma unroll
        for (int p=0;p<4;++p){
          int k0 = 8*q + 2*p;
          float v0 = (k0   < 10) ? lfb[k0*4096 + t] : 0.f;
          float v1 = (k0+1 < 10) ? lfb[(k0+1)*4096 + t] : 0.f;
          bw[p] = packbf2(v0, v1);
        }
        const short8 Bm = __builtin_bit_cast(short8, bw);
        #pragma unroll
        for (int m2=0;m2<8;++m2)
          pacc[n2][m2] = __builtin_amdgcn_mfma_f32_16x16x32_bf16(Am[m2], Bm, pacc[n2][m2],0,0,0);
      }
    }
  }

  // ------- conv layers i = 3..0: in-place, 2-ahead prefetch ring -----------
  #pragma unroll
  for (int i = 3; i >= 0; --i){
    short8 Ac0[3], Ac1[3];
    #pragma unroll
    for (int tp=0;tp<3;++tp){
      Ac0[tp] = *(const short8*)(convA + (((i*2+0)*3+tp)*64 + lane)*8);
      Ac1[tp] = *(const short8*)(convA + (((i*2+1)*3+tp)*64 + lane)*8);
    }
    const f32x4 cc0 = *(const f32x4*)&cAs[i][4*q];
    const f32x4 cc1 = *(const f32x4*)&cAs[i][16+4*q];
    float ysum[8];
    #pragma unroll
    for (int e=0;e<8;++e) ysum[e] = 0.f;

    short8 F0[3], F1[3], F2[3];
    {
      const u16* p = z + c16*40 + 8*q;                 // tile 0 taps
      F0[0] = *(const short8*)(p);
      F0[1] = *(const short8*)(p + 40);
      F0[2] = *(const short8*)(p + 80);
      const u16* p1 = z + (16 + c16)*40 + 8*q;         // tile 1 taps
      F1[0] = *(const short8*)(p1);
      F1[1] = *(const short8*)(p1 + 40);
      F1[2] = *(const short8*)(p1 + 80);
    }
    #pragma unroll
    for (int ct=0; ct<4; ++ct){
      short8* cur = (ct==0) ? F0 : (ct==1) ? F1 : (ct==2) ? F2 : F0;
      if (ct < 2){                                     // prefetch tile ct+2
        short8* nxt = (ct==0) ? F2 : F0;
        const u16* p = z + (16*(ct+2) + c16)*40 + 8*q;
        nxt[0] = *(const short8*)(p);
        nxt[1] = *(const short8*)(p + 40);
        nxt[2] = *(const short8*)(p + 80);
      }
      __builtin_amdgcn_sched_barrier(0);               // reads above writes
      f32x4 a0 = cc0, a1 = cc1;                        // BN shift in acc init
      a0 = __builtin_amdgcn_mfma_f32_16x16x32_bf16(Ac0[0], cur[0], a0, 0,0,0);
      a1 = __builtin_amdgcn_mfma_f32_16x16x32_bf16(Ac1[0], cur[0], a1, 0,0,0);
      a0 = __builtin_amdgcn_mfma_f32_16x16x32_bf16(Ac0[1], cur[1], a0, 0,0,0);
      a1 = __builtin_amdgcn_mfma_f32_16x16x32_bf16(Ac1[1], cur[1], a1, 0,0,0);
      a0 = __builtin_amdgcn_mfma_f32_16x16x32_bf16(Ac0[2], cur[2], a0, 0,0,0);
      a1 = __builtin_amdgcn_mfma_f32_16x16x32_bf16(Ac1[2], cur[2], a1, 0,0,0);
      const int wc = 16*ct + c16;
      const int t  = tbase + wc;
      const bool tok = (unsigned)t < 4096u;
      float y0[4], y1[4];
      #pragma unroll
      for (int r=0;r<4;++r){
        float u0 = fmaxf(a0[r], 0.f);
        float u1 = fmaxf(a1[r], 0.f);
        y0[r] = tok ? u0 : 0.f;
        y1[r] = tok ? u1 : 0.f;
      }
      if (PASS==1 && (ct==1 || ct==2)){
        #pragma unroll
        for (int r=0;r<4;++r){ ysum[r] += y0[r]; ysum[4+r] += y1[r]; }
      }
      uint2 w0; w0.x = packbf2(y0[0],y0[1]); w0.y = packbf2(y0[2],y0[3]);
      *(uint2*)&z[(wc+1)*40 + 4*q] = w0;
      if (q < 2){
        uint2 w1_; w1_.x = packbf2(y1[0],y1[1]); w1_.y = packbf2(y1[2],y1[3]);
        *(uint2*)&z[(wc+1)*40 + 16 + 4*q] = w1_;
      } else if (q == 2){
        z[(wc+1)*40 + 24] = f2bf(y1[0]);
      }
    }
    if (i > 0) *(u32*)&z[(lane+1)*40 + 26] = lpair[i-1];  // lf for next layer
    if constexpr (PASS==1){
      #pragma unroll
      for (int e=0;e<8;++e){
        float v = ysum[e];
        v += __shfl_xor(v,1); v += __shfl_xor(v,2); v += __shfl_xor(v,4); v += __shfl_xor(v,8);
        if (c16 == 0){
          int ch = (e>>2)*16 + 4*q + (e&3);
          if (ch < 25) atomicAdd(&accC[i*32+ch], v);
        }
      }
    }
    if constexpr (PASS==2){                 // GEMM kt=i : B = y_i from z
      short8 Am[8];
      #pragma unroll
      for (int m2=0;m2<8;++m2)
        Am[m2] = *(const short8*)(Ab + b*24576 + ((i*8+m2)*64 + lane)*8);
      #pragma unroll
      for (int n2=0;n2<2;++n2){
        const short8 Bm = *(const short8*)&z[(17+16*n2+c16)*40 + 8*q];
        #pragma unroll
        for (int m2=0;m2<8;++m2)
          pacc[n2][m2] = __builtin_amdgcn_mfma_f32_16x16x32_bf16(Am[m2], Bm, pacc[n2][m2],0,0,0);
      }
    }
  }

  if constexpr (PASS==1){
    __syncthreads();
    if (tid < 160) outpart[(b*32 + blk)*160 + tid] = accC[tid];
  }
  if constexpr (PASS==2){
    // final BN + relu + column-sum -> block-wide pooled reduction in LDS
    #pragma unroll
    for (int m2=0;m2<8;++m2){
      const f32x4 af = *(const f32x4*)&AfS[m2*16+4*q];
      const f32x4 bf = *(const f32x4*)&BfS[m2*16+4*q];
      #pragma unroll
      for (int r=0;r<4;++r){
        float s2 = fmaxf(pacc[0][m2][r]*af[r] + bf[r], 0.f)
                 + fmaxf(pacc[1][m2][r]*af[r] + bf[r], 0.f);
        s2 += __shfl_xor(s2,1); s2 += __shfl_xor(s2,2); s2 += __shfl_xor(s2,4); s2 += __shfl_xor(s2,8);
        if (c16 == 0) atomicAdd(&pooled[m2*16 + 4*q + r], s2);
      }
    }
    __syncthreads();
    if (tid < 128) outpart[(b*32 + blk)*128 + tid] = pooled[tid];
  }
}

// ---------------------------------------------------------------------------
// K2: gating MLP (redundant per block) + gated proj A-fragments.
// grid (128 batches, 6 kt); block (b,kt) builds its 4096 fragment entries.
// ---------------------------------------------------------------------------
__global__ void gate_kernel(const float* __restrict__ partialC,
                            const float* __restrict__ gw1, const float* __restrict__ gb1,
                            const float* __restrict__ gw2, const float* __restrict__ gb2,
                            const float* __restrict__ pf_w, const float* __restrict__ id_w,
                            u16* __restrict__ Ab)
{
  int b = blockIdx.x, kt = blockIdx.y, tid = threadIdx.x;
  __shared__ float avg[125], h1[31], g[6];
  if (tid < 160){
    float s = 0.f;
    for (int k = 0; k < 32; ++k) s += partialC[(b*32+k)*160 + tid];
    int sc = tid >> 5, ch = tid & 31;
    if (ch < 25) avg[sc*25+ch] = s * (1.f/4096.f);
  }
  __syncthreads();
  if (tid < 31){
    float s = gb1[tid];
    for (int c = 0; c < 125; ++c) s += avg[c] * gw1[tid*125 + c];
    h1[tid] = fmaxf(s, 0.f);
  }
  __syncthreads();
  if (tid < 5){
    float s = gb2[tid];
    for (int j = 0; j < 31; ++j) s += h1[j] * gw2[tid*31 + j];
    g[tid] = 1.f / (1.f + expf(-s));
  }
  if (tid == 5) g[5] = 1.f;
  __syncthreads();
  const float gk = g[kt];
  for (int x = tid; x < 4096; x += 256){
    int j = x & 7, l = (x>>3) & 63, mt = (x>>9) & 7;
    int m = mt*16 + (l & 15), k = (l>>4)*8 + j;
    float v = 0.f;
    if (m < 125){
      if (kt < 5){ if (k < 25) v = pf_w[m*125 + kt*25 + k] * gk; }
      else       { if (k < 10) v = id_w[m*10 + k]; }
    }
    Ab[b*24576 + kt*4096 + x] = f2bf(v);
  }
}

// ---------------------------------------------------------------------------
// K4: pooled mean -> LayerNorm -> fc1 + LeakyReLU(0.2) -> fc2 (256 threads)
// ---------------------------------------------------------------------------
__global__ void final_kernel(const float* __restrict__ pooledpart,
                             const float* __restrict__ ln_g, const float* __restrict__ ln_b,
                             const float* __restrict__ fc1_w, const float* __restrict__ fc1_b,
                             const float* __restrict__ fc2_w, const float* __restrict__ fc2_b,
                             float* __restrict__ out)
{
  int b = blockIdx.x, tid = threadIdx.x;
  __shared__ float ps[2][128], pl[128], nr[128], hh[64], st[2];
  {
    int c = tid & 127, h = tid >> 7;
    float s = 0.f;
    for (int k = h*16; k < h*16+16; ++k) s += pooledpart[(b*32+k)*128 + c];
    ps[h][c] = s;
  }
  __syncthreads();
  if (tid < 128) pl[tid] = (ps[0][tid] + ps[1][tid]) * (1.f/4096.f);
  __syncthreads();
  if (tid < 64){                                   // wave-parallel LN stats
    float v0 = (tid < 125) ? pl[tid] : 0.f;
    float v1 = (tid+64 < 125) ? pl[tid+64] : 0.f;
    float sm = v0 + v1;
    #pragma unroll
    for (int o = 1; o < 64; o <<= 1) sm += __shfl_xor(sm, o);
    float mu = sm * (1.f/125.f);
    float d0 = (tid < 125) ? (pl[tid]-mu) : 0.f;
    float d1 = (tid+64 < 125) ? (pl[tid+64]-mu) : 0.f;
    float sv = d0*d0 + d1*d1;
    #pragma unroll
    for (int o = 1; o < 64; o <<= 1) sv += __shfl_xor(sv, o);
    if (tid == 0){ st[0] = mu; st[1] = rsqrtf(sv*(1.f/125.f) + 1e-5f); }
  }
  __syncthreads();
  if (tid < 125) nr[tid] = (pl[tid] - st[0]) * st[1] * ln_g[tid] + ln_b[tid];
  else if (tid < 128) nr[tid] = 0.f;
  __syncthreads();
  {                                                // fc1: 4 threads per unit
    int u = tid >> 2, part = tid & 3;
    float s = 0.f;
    for (int c = part*32; c < part*32+32 && c < 125; ++c)
      s += nr[c] * fc1_w[u*125 + c];
    s += __shfl_xor(s, 1); s += __shfl_xor(s, 2);
    if (part == 0){
      float h = s + fc1_b[u];
      hh[u] = (h > 0.f) ? h : 0.2f*h;
    }
  }
  __syncthreads();
  if (tid < 2){
    float s = fc2_b[tid];
    for (int j = 0; j < 64; ++j) s += hh[j] * fc2_w[tid*64 + j];
    out[b*2 + tid] = s;
  }
}

// ---------------------------------------------------------------------------
extern "C" void kernel_launch(void* const* d_in, const int* in_sizes, int n_in,
                              void* d_out, int out_size, void* d_ws, size_t ws_size,
                              hipStream_t stream)
{
  const float* lf    = (const float*)d_in[0];
  const float* w1    = (const float*)d_in[1];
  const float* b1    = (const float*)d_in[2];
  const float* w3    = (const float*)d_in[3];
  const float* b3    = (const float*)d_in[4];
  const float* bn_g  = (const float*)d_in[5];
  const float* bn_b  = (const float*)d_in[6];
  const float* bn_m  = (const float*)d_in[7];
  const float* bn_v  = (const float*)d_in[8];
  const float* gw1   = (const float*)d_in[9];
  const float* gb1   = (const float*)d_in[10];
  const float* gw2   = (const float*)d_in[11];
  const float* gb2   = (const float*)d_in[12];
  const float* id_w  = (const float*)d_in[13];
  const float* id_b  = (const float*)d_in[14];
  const float* pf_w  = (const float*)d_in[15];
  const float* pf_b  = (const float*)d_in[16];
  const float* fbn_g = (const float*)d_in[17];
  const float* fbn_b = (const float*)d_in[18];
  const float* fbn_m = (const float*)d_in[19];
  const float* fbn_v = (const float*)d_in[20];
  const float* ln_g  = (const float*)d_in[21];
  const float* ln_b  = (const float*)d_in[22];
  const float* fc1_w = (const float*)d_in[23];
  const float* fc1_b = (const float*)d_in[24];
  const float* fc2_w = (const float*)d_in[25];
  const float* fc2_b = (const float*)d_in[26];

  char* ws = (char*)d_ws;
  float* partialC   = (float*)ws;                                   // 2,621,440 B
  float* pooledpart = (float*)(ws + 2621440);                       // 2,097,152 B
  u16*   Ab         = (u16*)(ws + 2621440 + 2097152);               // 6,291,456 B
  u16*   convA      = (u16*)(ws + 2621440 + 2097152 + 6291456);     //    24,576 B

  prep_kernel<<<48, 256, 0, stream>>>(w3, w1, b1, bn_g, bn_v, convA);
  pass_kernel<1><<<dim3(32,128), 256, 0, stream>>>(lf, w1, b1, b3, bn_g, bn_b,
      bn_m, bn_v, convA, Ab, pf_b, id_b, fbn_g, fbn_b, fbn_m, fbn_v, partialC);
  gate_kernel<<<dim3(128,6), 256, 0, stream>>>(partialC, gw1, gb1, gw2, gb2,
      pf_w, id_w, Ab);
  pass_kernel<2><<<dim3(32,128), 256, 0, stream>>>(lf, w1, b1, b3, bn_g, bn_b,
      bn_m, bn_v, convA, Ab, pf_b, id_b, fbn_g, fbn_b, fbn_m, fbn_v, pooledpart);
  final_kernel<<<128, 256, 0, stream>>>(pooledpart, ln_g, ln_b, fc1_w, fc1_b,
      fc2_w, fc2_b, (float*)d_out);
}